// Round 3
// baseline (638.110 us; speedup 1.0000x reference)
//
#include <hip/hip_runtime.h>
#include <stdint.h>
#include <stddef.h>

#define D0 4096
#define D1 1024
#define NOUT 1000
#define NB 64

// ---------------------------------------------------------------------------
// Spike pattern for uniform spike coding, N in [0,32] -> 32-bit cycle mask.
// Matches jnp: spacing = 32.f/N (fp32), spike at c iff fmod(c, spacing) < 1.
// floor(c/spacing) < N is always true for 0<N<32 (margin >= N/32 >> fp eps).
// ---------------------------------------------------------------------------
__device__ __forceinline__ uint32_t spike_pattern(int N) {
  if (N <= 0) return 0u;
  if (N >= 32) return 0xFFFFFFFFu;
  float spacing = 32.0f / (float)N;
  uint32_t m = 0;
  for (int c = 0; c < 32; ++c) {
    if (fmodf((float)c, spacing) < 1.0f) m |= (1u << c);
  }
  return m;
}

// ---------------------------------------------------------------------------
// Fused transpose: w0 (4096x4096) -> w0T[j][o]; w2 (1000x1024) -> w2T[j][o]
// (o padded to 1024 with zeros). 1-D grid: blocks [0,16384) = w0 tiles,
// [16384, 16384+1024) = w2 tiles.
// ---------------------------------------------------------------------------
__global__ void transpose_k(const float* __restrict__ w0, const float* __restrict__ w2,
                            float* __restrict__ w0T, float* __restrict__ w2T) {
  __shared__ float tile[32][33];
  int bid = blockIdx.x;
  int tx = threadIdx.x, ty = threadIdx.y;  // 32 x 8
  if (bid < 16384) {
    int j0 = (bid & 127) * 32;
    int o0 = (bid >> 7) * 32;
    for (int r = ty; r < 32; r += 8)
      tile[r][tx] = w0[(size_t)(o0 + r) * D0 + j0 + tx];
    __syncthreads();
    for (int r = ty; r < 32; r += 8)
      w0T[(size_t)(j0 + r) * D0 + o0 + tx] = tile[tx][r];
  } else {
    int b2 = bid - 16384;
    int j0 = (b2 & 31) * 32;
    int o0 = (b2 >> 5) * 32;
    for (int r = ty; r < 32; r += 8) {
      int o = o0 + r;
      tile[r][tx] = (o < NOUT) ? w2[(size_t)o * D1 + j0 + tx] : 0.0f;
    }
    __syncthreads();
    for (int r = ty; r < 32; r += 8)
      w2T[(size_t)(j0 + r) * D1 + o0 + tx] = tile[tx][r];
  }
}

// ---------------------------------------------------------------------------
// Core-0 sort, fused with rate->N encoding. Key = 33*chunk + N, chunk = j>>11
// (2 j-halves). perm[b][pos]=j sorted by key; starts[b][k], k in [0,67).
// Within-bucket order is non-deterministic (atomics) — perturbs fp64 bucket
// sums only at ~1e-16, irrelevant vs threshold gaps.
// ---------------------------------------------------------------------------
template <int D, int NCH, int CHSH>
__global__ void sort_enc_k(const float* __restrict__ x, const int* __restrict__ idx,
                           uint32_t* __restrict__ perm, int* __restrict__ starts) {
  constexpr int NBK = 33 * NCH;
  __shared__ int keys[D];
  __shared__ int hist[NBK];
  __shared__ int base[NBK + 1];
  __shared__ int cursor[NBK];
  int b = blockIdx.x, tid = threadIdx.x;
  for (int k = tid; k < NBK; k += 256) hist[k] = 0;
  __syncthreads();
  for (int j = tid; j < D; j += 256) {
    int N = (int)rintf(x[(size_t)b * D + idx[j]] * 32.0f);  // round-half-even
    int k = N + 33 * (j >> CHSH);
    keys[j] = k;
    atomicAdd(&hist[k], 1);
  }
  __syncthreads();
  if (tid == 0) {
    int s = 0;
    for (int k = 0; k < NBK; ++k) { base[k] = s; cursor[k] = s; s += hist[k]; }
    base[NBK] = s;
  }
  __syncthreads();
  for (int k = tid; k <= NBK; k += 256) starts[b * (NBK + 1) + k] = base[k];
  for (int j = tid; j < D; j += 256) {
    int pos = atomicAdd(&cursor[keys[j]], 1);
    perm[(size_t)b * D + pos] = (uint32_t)j;
  }
}

// ---------------------------------------------------------------------------
// Core-2 prep: avg_pool2d on exact spike counts -> N1 = rint(cnt4/4) (exact:
// cnt4 in [0,128], multiples of 1/4 exact in fp32; clip no-op), then counting
// sort of 1024 inputs, key = 33*(j>>8) + N1[idx2[j]] (4 j-quarters).
// ---------------------------------------------------------------------------
__global__ void pool_sort_k(const int* __restrict__ k0, const int* __restrict__ idx1,
                            const int* __restrict__ idx2,
                            uint32_t* __restrict__ perm, int* __restrict__ starts) {
  constexpr int NBK = 33 * 4;
  __shared__ int Nls[D1];
  __shared__ int keys[D1];
  __shared__ int hist[NBK];
  __shared__ int base[NBK + 1];
  __shared__ int cursor[NBK];
  int b = blockIdx.x, tid = threadIdx.x;
  for (int k = tid; k < NBK; k += 256) hist[k] = 0;
  for (int i = tid; i < D1; i += 256) {
    int c = i >> 4, h2 = (i >> 2) & 3, w2v = i & 3;
    int cnt = 0;
#pragma unroll
    for (int dh = 0; dh < 2; ++dh)
#pragma unroll
      for (int dw = 0; dw < 2; ++dw) {
        int q = c * 64 + (2 * h2 + dh) * 8 + (2 * w2v + dw);
        cnt += k0[(size_t)b * D0 + idx1[q]];
      }
    Nls[i] = (int)rintf((float)cnt * 0.25f);
  }
  __syncthreads();
  for (int j = tid; j < D1; j += 256) {
    int k = Nls[idx2[j]] + 33 * (j >> 8);
    keys[j] = k;
    atomicAdd(&hist[k], 1);
  }
  __syncthreads();
  if (tid == 0) {
    int s = 0;
    for (int k = 0; k < NBK; ++k) { base[k] = s; cursor[k] = s; s += hist[k]; }
    base[NBK] = s;
  }
  __syncthreads();
  for (int k = tid; k <= NBK; k += 256) starts[b * (NBK + 1) + k] = base[k];
  for (int j = tid; j < D1; j += 256) {
    int pos = atomicAdd(&cursor[keys[j]], 1);
    perm[(size_t)b * D1 + pos] = (uint32_t)j;
  }
}

// ---------------------------------------------------------------------------
// LIF bucket accumulation, fp64-exact, j-chunked for L2 residency.
// Block = (o-tile 256 cols, batch, z) with z = chunk + NCH*zslice and
// o_tile = x + gridDim.x*zslice. With XCD = linear%8 and z-major dispatch,
// any window of 2 consecutive z-groups touches exactly 4 MB of wt per XCD
// (= one XCD's L2). Per chunk: walk its 32 non-empty-key segments with
// 8-wide unrolled independent loads (perm/starts block-uniform -> scalar),
// scatter each fp64 bucket sum into contrib[t] per spike pattern, then one
// global fp64 atomic add per t. Exactly-2-chunk adds commute bit-exactly;
// 4-chunk (core 2) order perturbs only ~1e-16.
// ---------------------------------------------------------------------------
template <int D, int NCH>
__launch_bounds__(256, 4)
__global__ void lif_bucket_k(const float* __restrict__ wt, const uint32_t* __restrict__ perm,
                             const int* __restrict__ starts, double* __restrict__ contrib_g) {
  constexpr int NBK = 33 * NCH;
  __shared__ uint32_t pat[33];
  int tid = threadIdx.x;
  int zs = blockIdx.z / NCH, ch = blockIdx.z % NCH;
  int o = (blockIdx.x + gridDim.x * zs) * 256 + tid;
  int b = blockIdx.y;
  if (tid < 33) pat[tid] = spike_pattern(tid);
  __syncthreads();

  double contrib[32];
#pragma unroll
  for (int t = 0; t < 32; ++t) contrib[t] = 0.0;

  const uint32_t* permb = perm + (size_t)b * D;
  const int* st = starts + b * (NBK + 1);

  for (int kl = 1; kl <= 32; ++kl) {  // local key 0: empty pattern, skip
    int k = ch * 33 + kl;
    int s = st[k], e = st[k + 1];
    if (s == e) continue;  // uniform branch
    double a0 = 0.0, a1 = 0.0, a2 = 0.0, a3 = 0.0;
    int i = s;
    for (; i + 8 <= e; i += 8) {
      uint32_t j0 = permb[i + 0], j1 = permb[i + 1], j2 = permb[i + 2], j3 = permb[i + 3];
      uint32_t j4 = permb[i + 4], j5 = permb[i + 5], j6 = permb[i + 6], j7 = permb[i + 7];
      float f0 = wt[(size_t)j0 * D + o];
      float f1 = wt[(size_t)j1 * D + o];
      float f2 = wt[(size_t)j2 * D + o];
      float f3 = wt[(size_t)j3 * D + o];
      float f4 = wt[(size_t)j4 * D + o];
      float f5 = wt[(size_t)j5 * D + o];
      float f6 = wt[(size_t)j6 * D + o];
      float f7 = wt[(size_t)j7 * D + o];
      a0 += (double)f0; a1 += (double)f1; a2 += (double)f2; a3 += (double)f3;
      a0 += (double)f4; a1 += (double)f5; a2 += (double)f6; a3 += (double)f7;
    }
    for (; i < e; ++i)
      a0 += (double)wt[(size_t)permb[i] * D + o];
    double acc = (a0 + a1) + (a2 + a3);
    uint32_t m = pat[kl];
#pragma unroll
    for (int t = 0; t < 32; ++t)
      contrib[t] += ((m >> t) & 1u) ? acc : 0.0;
  }

#pragma unroll
  for (int t = 0; t < 32; ++t)
    unsafeAtomicAdd(&contrib_g[((size_t)b * 32 + t) * D + o], contrib[t]);
}

// ---------------------------------------------------------------------------
// Membrane scan: memb += contrib[t]; fired iff threshold < memb; subtract
// reset; emit spike count.
// ---------------------------------------------------------------------------
template <int D>
__global__ void scan_k(const double* __restrict__ contrib_g, const float* __restrict__ thr_p,
                       int* __restrict__ cnt_out) {
  int i = blockIdx.x * 256 + threadIdx.x;
  int b = i / D, o = i % D;  // D power of two -> shifts
  double th = (double)thr_p[0];
  double memb = 0.0;
  int cnt = 0;
#pragma unroll
  for (int t = 0; t < 32; ++t) {
    memb += contrib_g[((size_t)b * 32 + t) * D + o];
    if (memb > th) { memb -= th; ++cnt; }  // strict: threshold < memb
  }
  cnt_out[(size_t)b * D + o] = cnt;
}

__global__ void write_out_k(const int* __restrict__ cnt2, const int* __restrict__ idx_out,
                            float* __restrict__ out) {
  int i = blockIdx.x * 256 + threadIdx.x;
  if (i >= NB * NOUT) return;
  int b = i / NOUT;
  int r = i - b * NOUT;
  out[i] = (float)cnt2[(size_t)b * D1 + idx_out[r]];
}

// ---------------------------------------------------------------------------
extern "C" void kernel_launch(void* const* d_in, const int* in_sizes, int n_in,
                              void* d_out, int out_size, void* d_ws, size_t ws_size,
                              hipStream_t stream) {
  const float* x      = (const float*)d_in[0];
  const float* w0     = (const float*)d_in[1];
  const float* t0     = (const float*)d_in[2];
  const float* w2     = (const float*)d_in[3];
  const float* t2     = (const float*)d_in[4];
  const int*   idx1   = (const int*)d_in[6];
  const int*   idx0   = (const int*)d_in[5];
  const int*   idx2   = (const int*)d_in[7];
  const int*   idx_out= (const int*)d_in[8];
  float* out = (float*)d_out;

  char* ws = (char*)d_ws;
  float*    w0T     = (float*)ws;    ws += (size_t)D0 * D0 * 4;        // 64 MB
  float*    w2T     = (float*)ws;    ws += (size_t)D1 * D1 * 4;        // 4 MB
  double*   contrib0= (double*)ws;   ws += (size_t)NB * 32 * D0 * 8;   // 67 MB
  double*   contrib2= (double*)ws;   ws += (size_t)NB * 32 * D1 * 8;   // 17 MB (adjacent for one memset)
  uint32_t* perm0   = (uint32_t*)ws; ws += (size_t)NB * D0 * 4;
  uint32_t* perm2   = (uint32_t*)ws; ws += (size_t)NB * D1 * 4;
  int*      k0      = (int*)ws;      ws += (size_t)NB * D0 * 4;
  int*      cnt2    = (int*)ws;      ws += (size_t)NB * D1 * 4;
  int*      starts0 = (int*)ws;      ws += (size_t)NB * 67 * 4;
  int*      starts2 = (int*)ws;      ws += (size_t)NB * 133 * 4;

  transpose_k<<<16384 + 1024, dim3(32, 8), 0, stream>>>(w0, w2, w0T, w2T);
  sort_enc_k<D0, 2, 11><<<NB, 256, 0, stream>>>(x, idx0, perm0, starts0);
  hipMemsetAsync(contrib0, 0, (size_t)NB * 32 * (D0 + D1) * 8, stream);
  // grid (8, NB, 4): z = jhalf + 2*zslice, o_tile = x + 8*zslice. Any window
  // of 2 consecutive z-groups = 4 MB wt per XCD -> L2-resident.
  lif_bucket_k<D0, 2><<<dim3(8, NB, 4), 256, 0, stream>>>(w0T, perm0, starts0, contrib0);
  scan_k<D0><<<NB * D0 / 256, 256, 0, stream>>>(contrib0, t0, k0);
  pool_sort_k<<<NB, 256, 0, stream>>>(k0, idx1, idx2, perm2, starts2);
  lif_bucket_k<D1, 4><<<dim3(4, NB, 4), 256, 0, stream>>>(w2T, perm2, starts2, contrib2);
  scan_k<D1><<<NB * D1 / 256, 256, 0, stream>>>(contrib2, t2, cnt2);
  write_out_k<<<(NB * NOUT + 255) / 256, 256, 0, stream>>>(cnt2, idx_out, out);
}